// Round 1
// baseline (6668.978 us; speedup 1.0000x reference)
//
#include <hip/hip_runtime.h>
#include <math.h>

// Problem constants
#define BB 2
#define SS 1024
#define DIM 2048
#define HH 16
#define QR 1536
#define KVR 512
#define DN 128
#define DR 64
#define DV 128
#define QKD 192          // DN + DR
#define NT (BB*SS)       // 2048 tokens
#define TS 32

// ---------------- GEMM: C = scale * A @ B^T (+bias) (+causal) ----------------
// A: M x K row-major (lda), Bm: N x K row-major (ldb), C: M x N (ldc)
__global__ void gemm_nt_k(const float* __restrict__ A, int lda, long sA,
                          const float* __restrict__ Bm, int ldb, long sB,
                          float* __restrict__ C, int ldc, long sC,
                          int M, int N, int K,
                          const float* __restrict__ bias, float scale, int causal)
{
  A  += (long)blockIdx.z * sA;
  Bm += (long)blockIdx.z * sB;
  C  += (long)blockIdx.z * sC;
  __shared__ float As[TS][TS+1];
  __shared__ float Bs[TS][TS+1];
  const int tid = threadIdx.y * 16 + threadIdx.x;
  const int row0 = blockIdx.y * TS, col0 = blockIdx.x * TS;
  float acc[2][2] = {{0.f,0.f},{0.f,0.f}};
  for (int k0 = 0; k0 < K; k0 += TS) {
#pragma unroll
    for (int i = 0; i < 4; ++i) {
      int idx = tid + i * 256;
      int r = idx >> 5, c = idx & 31;
      int gk = k0 + c;
      int ga = row0 + r;
      As[r][c] = (ga < M && gk < K) ? A[(long)ga * lda + gk] : 0.f;
      int gb = col0 + r;
      Bs[r][c] = (gb < N && gk < K) ? Bm[(long)gb * ldb + gk] : 0.f;
    }
    __syncthreads();
#pragma unroll
    for (int kk = 0; kk < TS; ++kk) {
      float a0 = As[threadIdx.y*2+0][kk];
      float a1 = As[threadIdx.y*2+1][kk];
      float b0 = Bs[threadIdx.x*2+0][kk];
      float b1 = Bs[threadIdx.x*2+1][kk];
      acc[0][0] += a0*b0; acc[0][1] += a0*b1;
      acc[1][0] += a1*b0; acc[1][1] += a1*b1;
    }
    __syncthreads();
  }
#pragma unroll
  for (int i = 0; i < 2; ++i)
#pragma unroll
    for (int j = 0; j < 2; ++j) {
      int r = row0 + threadIdx.y*2 + i;
      int c = col0 + threadIdx.x*2 + j;
      if (r < M && c < N) {
        float v = acc[i][j] * scale;
        if (bias) v += bias[c];
        if (causal && r < c) v += -1e9f;
        C[(long)r * ldc + c] = v;
      }
    }
}

// ---------------- GEMM: C = A @ B (+bias), B row-major K x N ----------------
__global__ void gemm_nn_k(const float* __restrict__ A, int lda, long sA,
                          const float* __restrict__ Bm, int ldb, long sB,
                          float* __restrict__ C, int ldc, long sC,
                          int M, int N, int K,
                          const float* __restrict__ bias, float scale)
{
  A  += (long)blockIdx.z * sA;
  Bm += (long)blockIdx.z * sB;
  C  += (long)blockIdx.z * sC;
  __shared__ float As[TS][TS+1];
  __shared__ float Bs[TS][TS+1];
  const int tid = threadIdx.y * 16 + threadIdx.x;
  const int row0 = blockIdx.y * TS, col0 = blockIdx.x * TS;
  float acc[2][2] = {{0.f,0.f},{0.f,0.f}};
  for (int k0 = 0; k0 < K; k0 += TS) {
#pragma unroll
    for (int i = 0; i < 4; ++i) {
      int idx = tid + i * 256;
      int r = idx >> 5, c = idx & 31;
      // A tile: rows x k
      int ga = row0 + r, gk = k0 + c;
      As[r][c] = (ga < M && gk < K) ? A[(long)ga * lda + gk] : 0.f;
      // B tile: k x cols
      int gk2 = k0 + r, gn = col0 + c;
      Bs[r][c] = (gk2 < K && gn < N) ? Bm[(long)gk2 * ldb + gn] : 0.f;
    }
    __syncthreads();
#pragma unroll
    for (int kk = 0; kk < TS; ++kk) {
      float a0 = As[threadIdx.y*2+0][kk];
      float a1 = As[threadIdx.y*2+1][kk];
      float b0 = Bs[kk][threadIdx.x*2+0];
      float b1 = Bs[kk][threadIdx.x*2+1];
      acc[0][0] += a0*b0; acc[0][1] += a0*b1;
      acc[1][0] += a1*b0; acc[1][1] += a1*b1;
    }
    __syncthreads();
  }
#pragma unroll
  for (int i = 0; i < 2; ++i)
#pragma unroll
    for (int j = 0; j < 2; ++j) {
      int r = row0 + threadIdx.y*2 + i;
      int c = col0 + threadIdx.x*2 + j;
      if (r < M && c < N) {
        float v = acc[i][j] * scale;
        if (bias) v += bias[c];
        C[(long)r * ldc + c] = v;
      }
    }
}

// ---------------- RMSNorm over rows ----------------
// in: row-major with ldin, out with ldout; N = normalized width
__global__ void rmsnorm_k(const float* __restrict__ in, int ldin,
                          float* __restrict__ out, int ldout,
                          const float* __restrict__ w, int N)
{
  long row = blockIdx.x;
  const float* x = in + row * ldin;
  float* y = out + row * ldout;
  float ss = 0.f;
  for (int i = threadIdx.x; i < N; i += blockDim.x) { float v = x[i]; ss += v*v; }
  for (int off = 32; off > 0; off >>= 1) ss += __shfl_down(ss, off);
  __shared__ float red[4];
  int lane = threadIdx.x & 63, wid = threadIdx.x >> 6;
  if (lane == 0) red[wid] = ss;
  __syncthreads();
  if (threadIdx.x == 0) {
    float t = 0.f;
    for (int i = 0; i < (int)(blockDim.x >> 6); ++i) t += red[i];
    red[0] = rsqrtf(t / (float)N + 1e-6f);
  }
  __syncthreads();
  float r = red[0];
  for (int i = threadIdx.x; i < N; i += blockDim.x) y[i] = x[i] * r * w[i];
}

// ---------------- RoPE on q_pe (in-place in qb buffer) ----------------
// qb: NT x (H*QKD); pe at [h*QKD + DN .. +DR)
__global__ void rope_q_k(float* __restrict__ qb,
                         const float* __restrict__ cosT, const float* __restrict__ sinT)
{
  int idx = blockIdx.x * blockDim.x + threadIdx.x;   // NT*H*32
  if (idx >= NT*HH*32) return;
  int d = idx & 31;
  int h = (idx >> 5) & (HH-1);
  int row = idx >> 9;
  int s = row & (SS-1);
  float* p = qb + (long)row * (HH*QKD) + h*QKD + DN;
  float x1 = p[d], x2 = p[d+32];
  float c1 = cosT[s*DR + d],      s1 = sinT[s*DR + d];
  float c2 = cosT[s*DR + 32 + d], s2 = sinT[s*DR + 32 + d];
  p[d]    = x1*c1 - x2*s1;
  p[d+32] = x2*c2 + x1*s2;
}

// ---------------- RoPE on k_pe: kv_all[:,512:576] -> kcat[:,512:576] ----------------
__global__ void rope_k_k(const float* __restrict__ kv_all, float* __restrict__ kcat,
                         const float* __restrict__ cosT, const float* __restrict__ sinT)
{
  int idx = blockIdx.x * blockDim.x + threadIdx.x;   // NT*32
  if (idx >= NT*32) return;
  int d = idx & 31;
  int row = idx >> 5;
  int s = row & (SS-1);
  const float* p = kv_all + (long)row * (KVR+DR) + KVR;
  float x1 = p[d], x2 = p[d+32];
  float c1 = cosT[s*DR + d],      s1 = sinT[s*DR + d];
  float c2 = cosT[s*DR + 32 + d], s2 = sinT[s*DR + 32 + d];
  float* o = kcat + (long)row * (KVR+DR) + KVR;
  o[d]    = x1*c1 - x2*s1;
  o[d+32] = x2*c2 + x1*s2;
}

// ---------------- copy q_pe (head h) into qcat[:,512:576] ----------------
__global__ void copy_pe_k(const float* __restrict__ qb, float* __restrict__ qcat, int h)
{
  int idx = blockIdx.x * blockDim.x + threadIdx.x;   // NT*DR
  if (idx >= NT*DR) return;
  int d = idx & (DR-1);
  int row = idx >> 6;
  qcat[(long)row * (KVR+DR) + KVR + d] = qb[(long)row * (HH*QKD) + h*QKD + DN + d];
}

// ---------------- row softmax in place ----------------
__global__ void softmax_k(float* __restrict__ sc, int cols)
{
  long row = blockIdx.x;
  float* p = sc + row * cols;
  __shared__ float red[4];
  int lane = threadIdx.x & 63, wid = threadIdx.x >> 6;

  float mx = -1e30f;
  for (int i = threadIdx.x; i < cols; i += blockDim.x) mx = fmaxf(mx, p[i]);
  for (int off = 32; off > 0; off >>= 1) mx = fmaxf(mx, __shfl_down(mx, off));
  if (lane == 0) red[wid] = mx;
  __syncthreads();
  if (threadIdx.x == 0) {
    float t = red[0];
    for (int i = 1; i < (int)(blockDim.x >> 6); ++i) t = fmaxf(t, red[i]);
    red[0] = t;
  }
  __syncthreads();
  mx = red[0];
  __syncthreads();

  float sum = 0.f;
  for (int i = threadIdx.x; i < cols; i += blockDim.x) {
    float e = __expf(p[i] - mx);
    p[i] = e;
    sum += e;
  }
  for (int off = 32; off > 0; off >>= 1) sum += __shfl_down(sum, off);
  if (lane == 0) red[wid] = sum;
  __syncthreads();
  if (threadIdx.x == 0) {
    float t = 0.f;
    for (int i = 0; i < (int)(blockDim.x >> 6); ++i) t += red[i];
    red[0] = 1.f / t;
  }
  __syncthreads();
  float inv = red[0];
  for (int i = threadIdx.x; i < cols; i += blockDim.x) p[i] *= inv;
}

// ---------------- launch ----------------
extern "C" void kernel_launch(void* const* d_in, const int* in_sizes, int n_in,
                              void* d_out, int out_size, void* d_ws, size_t ws_size,
                              hipStream_t stream) {
  const float* x        = (const float*)d_in[0];
  // d_in[1] = mask (causal; applied analytically)
  const float* wq_a_w   = (const float*)d_in[2];
  const float* wq_a_b   = (const float*)d_in[3];
  const float* q_norm_w = (const float*)d_in[4];
  const float* wq_b_w   = (const float*)d_in[5];
  const float* wq_b_b   = (const float*)d_in[6];
  const float* wkv_a_w  = (const float*)d_in[7];
  const float* wkv_a_b  = (const float*)d_in[8];
  const float* kv_norm_w= (const float*)d_in[9];
  const float* wk_b_w   = (const float*)d_in[10];
  const float* wo_w     = (const float*)d_in[11];
  const float* wo_b     = (const float*)d_in[12];
  const float* cosT     = (const float*)d_in[13];
  const float* sinT     = (const float*)d_in[14];
  float* out = (float*)d_out;

  float* ws = (float*)d_ws;
  float* qn     = ws;                  // NT*QR       = 3,145,728
  float* qb     = qn     + (long)NT*QR;        // NT*H*QKD    = 6,291,456
  float* kv_all = qb     + (long)NT*HH*QKD;    // NT*576      = 1,179,648
  float* kcat   = kv_all + (long)NT*(KVR+DR);  // NT*576
  float* qcat   = kcat   + (long)NT*(KVR+DR);  // NT*576
  float* scores = qcat   + (long)NT*(KVR+DR);  // B*S*S       = 2,097,152
  float* o_mid  = scores + (long)BB*SS*SS;     // NT*512      = 1,048,576
  float* o_head = o_mid  + (long)NT*KVR;       // NT*H*DV     = 4,194,304

  dim3 blk(16,16);
  const float inv_sqrt = 0.07216878364870323f;  // 1/sqrt(192)

  // q_a: qn = x @ wq_a_w^T + b    (2048 x 1536, K=2048)
  gemm_nt_k<<<dim3(QR/TS, NT/TS, 1), blk, 0, stream>>>(
      x, DIM, 0, wq_a_w, DIM, 0, qn, QR, 0, NT, QR, DIM, wq_a_b, 1.f, 0);
  // rmsnorm qn in place
  rmsnorm_k<<<NT, 256, 0, stream>>>(qn, QR, qn, QR, q_norm_w, QR);
  // q_b: qb = qn @ wq_b_w^T + b   (2048 x 3072, K=1536)
  gemm_nt_k<<<dim3(HH*QKD/TS, NT/TS, 1), blk, 0, stream>>>(
      qn, QR, 0, wq_b_w, QR, 0, qb, HH*QKD, 0, NT, HH*QKD, QR, wq_b_b, 1.f, 0);
  // RoPE q_pe in place
  rope_q_k<<<(NT*HH*32 + 255)/256, 256, 0, stream>>>(qb, cosT, sinT);
  // kv_a: kv_all = x @ wkv_a_w^T + b  (2048 x 576, K=2048)
  gemm_nt_k<<<dim3((KVR+DR)/TS, NT/TS, 1), blk, 0, stream>>>(
      x, DIM, 0, wkv_a_w, DIM, 0, kv_all, KVR+DR, 0, NT, KVR+DR, DIM, wkv_a_b, 1.f, 0);
  // kvn -> kcat[:, :512]
  rmsnorm_k<<<NT, 256, 0, stream>>>(kv_all, KVR+DR, kcat, KVR+DR, kv_norm_w, KVR);
  // RoPE k_pe -> kcat[:, 512:576]
  rope_k_k<<<(NT*32 + 255)/256, 256, 0, stream>>>(kv_all, kcat, cosT, sinT);

  for (int h = 0; h < HH; ++h) {
    // q_abs: qcat[:, :512] = q_nope_h @ wkv_b[h,:128,:]   (NN, K=128)
    gemm_nn_k<<<dim3(KVR/TS, NT/TS, 1), blk, 0, stream>>>(
        qb + h*QKD, HH*QKD, 0, wk_b_w + (long)h*(DN+DV)*KVR, KVR, 0,
        qcat, KVR+DR, 0, NT, KVR, DN, nullptr, 1.f);
    // qcat[:, 512:576] = q_pe_h
    copy_pe_k<<<(NT*DR + 255)/256, 256, 0, stream>>>(qb, qcat, h);
    // scores[b] = qcat[b] @ kcat[b]^T / sqrt(192) + causal   (z = B)
    gemm_nt_k<<<dim3(SS/TS, SS/TS, BB), blk, 0, stream>>>(
        qcat, KVR+DR, (long)SS*(KVR+DR), kcat, KVR+DR, (long)SS*(KVR+DR),
        scores, SS, (long)SS*SS, SS, SS, KVR+DR, nullptr, inv_sqrt, 1);
    // softmax rows
    softmax_k<<<BB*SS, 256, 0, stream>>>(scores, SS);
    // o_mid[b] = P[b] @ kvn[b]  (NN, K=1024)
    gemm_nn_k<<<dim3(KVR/TS, SS/TS, BB), blk, 0, stream>>>(
        scores, SS, (long)SS*SS, kcat, KVR+DR, (long)SS*(KVR+DR),
        o_mid, KVR, (long)SS*KVR, SS, KVR, SS, nullptr, 1.f);
    // o_head[:, h*128:(h+1)*128] = o_mid @ wkv_b[h,128:256,:]^T  (NT, K=512)
    gemm_nt_k<<<dim3(DV/TS, NT/TS, 1), blk, 0, stream>>>(
        o_mid, KVR, 0, wk_b_w + ((long)h*(DN+DV) + DN)*KVR, KVR, 0,
        o_head + h*DV, HH*DV, 0, NT, DV, KVR, nullptr, 1.f, 0);
  }

  // out = o_head @ wo_w^T + wo_b   (2048 x 2048, K=2048)
  gemm_nt_k<<<dim3(DIM/TS, NT/TS, 1), blk, 0, stream>>>(
      o_head, HH*DV, 0, wo_w, DIM, 0, out, DIM, 0, NT, DIM, HH*DV, wo_b, 1.f, 0);
}

// Round 2
// 912.681 us; speedup vs baseline: 7.3070x; 7.3070x over previous
//
#include <hip/hip_runtime.h>
#include <hip/hip_bf16.h>
#include <math.h>

#define BB 2
#define SS 1024
#define DIM 2048
#define HH 16
#define QR 1536
#define KVR 512
#define DN 128
#define DR 64
#define DV 128
#define QKD 192
#define NT (BB*SS)
#define GG 2   // heads per group

typedef __attribute__((ext_vector_type(8))) short bhalf8;
typedef __attribute__((ext_vector_type(4))) float f32x4;

__device__ __forceinline__ unsigned short f2b(float f) {
  union { float f; unsigned u; } v; v.f = f;
  unsigned r = v.u + 0x7fffu + ((v.u >> 16) & 1u);
  return (unsigned short)(r >> 16);
}
__device__ __forceinline__ float b2f(unsigned short h) {
  union { unsigned u; float f; } v; v.u = ((unsigned)h) << 16;
  return v.f;
}

__device__ __forceinline__ void gload16(const void* g, void* l) {
  __builtin_amdgcn_global_load_lds((const __attribute__((address_space(1))) void*)g,
                                   (__attribute__((address_space(3))) void*)l, 16, 0, 0);
}

// ---------------- f32 -> bf16 convert (4 elems/thread) ----------------
__global__ void cvt_k(const float* __restrict__ in, unsigned short* __restrict__ out, long n4) {
  long i = (long)blockIdx.x * 256 + threadIdx.x;
  if (i >= n4) return;
  float4 v = ((const float4*)in)[i];
  ushort4 o; o.x = f2b(v.x); o.y = f2b(v.y); o.z = f2b(v.z); o.w = f2b(v.w);
  ((ushort4*)out)[i] = o;
}

// wkT[h][c][d] = bf16(wk[h][d][c]), d<128, c<512
__global__ void wkT_k(const float* __restrict__ wk, unsigned short* __restrict__ wkT) {
  int idx = blockIdx.x * 256 + threadIdx.x;   // 16*512*128
  int d = idx & 127, c = (idx >> 7) & 511, h = idx >> 16;
  wkT[idx] = f2b(wk[((long)h * 256 + d) * 512 + c]);
}

// kcatT[b][c][t] = kcatb[b][t][c], c<512
__global__ void kcT_k(const unsigned short* __restrict__ kc, unsigned short* __restrict__ kt) {
  int idx = blockIdx.x * 256 + threadIdx.x;   // 2*512*1024
  int t = idx & 1023, c = (idx >> 10) & 511, b = idx >> 19;
  kt[idx] = kc[((long)b * SS + t) * 576 + c];
}

// ---------------- MFMA GEMM: C = scale*A@B^T + bias (+causal) ----------------
// A: M x K bf16 (lda), B: N x K bf16 (ldb). 128x128 tile, BK=32, 4 waves.
template<int OBF, int CAUSAL>
__global__ __launch_bounds__(256) void gemm_mfma(
    const unsigned short* __restrict__ A, int lda, long sA,
    const unsigned short* __restrict__ B, int ldb, long sB, int bmod,
    void* __restrict__ C, int ldc, long sC,
    int M, int N, int K, const float* __restrict__ bias, float scale)
{
  __shared__ unsigned short As[4096];
  __shared__ unsigned short Bs[4096];
  const int z = blockIdx.z;
  A += (long)z * sA;
  B += (long)(bmod ? (z % bmod) : z) * sB;
  const int tid = threadIdx.x, l = tid & 63, w = tid >> 6;
  const int wr = w >> 1, wc = w & 1;
  const int m0 = blockIdx.y * 128, n0 = blockIdx.x * 128;
  const int rA = l >> 2;            // row within 16-row chunk
  const int c8 = (l & 3) << 3;      // k offset within BK

  f32x4 acc[4][4] = {};

  const unsigned short* Ab0 = A + (long)(m0 + w * 16 + rA) * lda + c8;
  const unsigned short* Ab1 = Ab0 + (long)64 * lda;
  int nb0 = n0 + w * 16 + rA;      if (nb0 > N - 1) nb0 = N - 1;
  int nb1 = n0 + 64 + w * 16 + rA; if (nb1 > N - 1) nb1 = N - 1;
  const unsigned short* Bb0 = B + (long)nb0 * ldb + c8;
  const unsigned short* Bb1 = B + (long)nb1 * ldb + c8;

  const int ko = (l >> 4) << 3;

  for (int k0 = 0; k0 < K; k0 += 32) {
    gload16(Ab0 + k0, &As[w * 512]);
    gload16(Ab1 + k0, &As[(w + 4) * 512]);
    gload16(Bb0 + k0, &Bs[w * 512]);
    gload16(Bb1 + k0, &Bs[(w + 4) * 512]);
    __syncthreads();
    bhalf8 af[4], bv[4];
#pragma unroll
    for (int m = 0; m < 4; ++m) {
      af[m] = *(const bhalf8*)&As[(wr * 64 + m * 16 + (l & 15)) * 32 + ko];
      bv[m] = *(const bhalf8*)&Bs[(wc * 64 + m * 16 + (l & 15)) * 32 + ko];
    }
#pragma unroll
    for (int m = 0; m < 4; ++m)
#pragma unroll
      for (int n = 0; n < 4; ++n)
        acc[m][n] = __builtin_amdgcn_mfma_f32_16x16x32_bf16(af[m], bv[n], acc[m][n], 0, 0, 0);
    __syncthreads();
  }

  const int ro = (l >> 4) << 2;
  const int co = l & 15;
#pragma unroll
  for (int m = 0; m < 4; ++m) {
    int row = m0 + wr * 64 + m * 16 + ro;
#pragma unroll
    for (int n = 0; n < 4; ++n) {
      int col = n0 + wc * 64 + n * 16 + co;
      if (col < N) {
        float bvl = bias ? bias[col] : 0.f;
#pragma unroll
        for (int r = 0; r < 4; ++r) {
          float v = acc[m][n][r] * scale + bvl;
          if (CAUSAL && (row + r) < col) v += -1e9f;
          long off = (long)z * sC + (long)(row + r) * ldc + col;
          if (OBF) ((unsigned short*)C)[off] = f2b(v);
          else     ((float*)C)[off] = v;
        }
      }
    }
  }
}

// ---------------- RMSNorm fp32 -> bf16 ----------------
__global__ void rmsnorm_k(const float* __restrict__ in, int ldin,
                          unsigned short* __restrict__ out, int ldout,
                          const float* __restrict__ w, int N) {
  long row = blockIdx.x;
  const float* x = in + row * ldin;
  unsigned short* y = out + row * ldout;
  float ss = 0.f;
  for (int i = threadIdx.x; i < N; i += 256) { float u = x[i]; ss += u * u; }
  for (int o = 32; o > 0; o >>= 1) ss += __shfl_down(ss, o);
  __shared__ float red[4];
  int lane = threadIdx.x & 63, wid = threadIdx.x >> 6;
  if (lane == 0) red[wid] = ss;
  __syncthreads();
  float r = rsqrtf((red[0] + red[1] + red[2] + red[3]) / (float)N + 1e-6f);
  for (int i = threadIdx.x; i < N; i += 256) y[i] = f2b(x[i] * r * w[i]);
}

// ---------------- RoPE on q_pe, in-place bf16 ----------------
__global__ void rope_q_k(unsigned short* __restrict__ qb,
                         const float* __restrict__ cosT, const float* __restrict__ sinT) {
  int idx = blockIdx.x * 256 + threadIdx.x;   // NT*HH*32
  int d = idx & 31, h = (idx >> 5) & 15, t = idx >> 9, s = t & (SS - 1);
  unsigned short* p = qb + (long)t * 3072 + h * QKD + DN;
  float x1 = b2f(p[d]), x2 = b2f(p[d + 32]);
  float c1 = cosT[s * DR + d],      s1 = sinT[s * DR + d];
  float c2 = cosT[s * DR + 32 + d], s2 = sinT[s * DR + 32 + d];
  p[d]      = f2b(x1 * c1 - x2 * s1);
  p[d + 32] = f2b(x2 * c2 + x1 * s2);
}

// ---------------- RoPE on k_pe: kv_f32 -> kcatb cols 512..575 ----------------
__global__ void rope_k_k(const float* __restrict__ kv, unsigned short* __restrict__ kc,
                         const float* __restrict__ cosT, const float* __restrict__ sinT) {
  int idx = blockIdx.x * 256 + threadIdx.x;   // NT*32
  int d = idx & 31, t = idx >> 5, s = t & (SS - 1);
  const float* p = kv + (long)t * 576 + 512;
  float x1 = p[d], x2 = p[d + 32];
  float c1 = cosT[s * DR + d],      s1 = sinT[s * DR + d];
  float c2 = cosT[s * DR + 32 + d], s2 = sinT[s * DR + 32 + d];
  unsigned short* o = kc + (long)t * 576 + 512;
  o[d]      = f2b(x1 * c1 - x2 * s1);
  o[d + 32] = f2b(x2 * c2 + x1 * s2);
}

// ---------------- copy q_pe (heads h0..h0+GG) into qcat cols 512..575 ----------------
__global__ void copy_pe_k(const unsigned short* __restrict__ qb,
                          unsigned short* __restrict__ qcat, int h0) {
  int idx = blockIdx.x * 256 + threadIdx.x;   // GG*NT*64
  int d = idx & 63, t = (idx >> 6) & (NT - 1), z = idx >> 17;
  qcat[((long)z * NT + t) * 576 + 512 + d] = qb[(long)t * 3072 + (h0 + z) * QKD + DN + d];
}

// ---------------- softmax fp32 row -> bf16 in place ----------------
__global__ void softmax_k(float* __restrict__ sc) {
  long row = blockIdx.x;
  float* p = sc + row * SS;
  const int t = threadIdx.x;
  float v[4];
#pragma unroll
  for (int j = 0; j < 4; ++j) v[j] = p[t + j * 256];
  float mx = fmaxf(fmaxf(v[0], v[1]), fmaxf(v[2], v[3]));
  for (int o = 32; o > 0; o >>= 1) mx = fmaxf(mx, __shfl_down(mx, o));
  __shared__ float red[4];
  __shared__ float red2[4];
  int lane = t & 63, wid = t >> 6;
  if (lane == 0) red[wid] = mx;
  __syncthreads();
  mx = fmaxf(fmaxf(red[0], red[1]), fmaxf(red[2], red[3]));
  float sum = 0.f;
#pragma unroll
  for (int j = 0; j < 4; ++j) { v[j] = __expf(v[j] - mx); sum += v[j]; }
  for (int o = 32; o > 0; o >>= 1) sum += __shfl_down(sum, o);
  if (lane == 0) red2[wid] = sum;
  __syncthreads();
  float inv = 1.f / (red2[0] + red2[1] + red2[2] + red2[3]);
  unsigned short* o16 = (unsigned short*)p;
#pragma unroll
  for (int j = 0; j < 4; ++j) o16[t + j * 256] = f2b(v[j] * inv);
}

// ---------------- launch ----------------
extern "C" void kernel_launch(void* const* d_in, const int* in_sizes, int n_in,
                              void* d_out, int out_size, void* d_ws, size_t ws_size,
                              hipStream_t stream) {
  const float* x        = (const float*)d_in[0];
  const float* wq_a_w   = (const float*)d_in[2];
  const float* wq_a_b   = (const float*)d_in[3];
  const float* q_norm_w = (const float*)d_in[4];
  const float* wq_b_w   = (const float*)d_in[5];
  const float* wq_b_b   = (const float*)d_in[6];
  const float* wkv_a_w  = (const float*)d_in[7];
  const float* wkv_a_b  = (const float*)d_in[8];
  const float* kv_norm_w= (const float*)d_in[9];
  const float* wk_b_w   = (const float*)d_in[10];
  const float* wo_w     = (const float*)d_in[11];
  const float* wo_bias  = (const float*)d_in[12];
  const float* cosT     = (const float*)d_in[13];
  const float* sinT     = (const float*)d_in[14];
  float* out = (float*)d_out;

  char* W = (char*)d_ws;
  // persistent
  unsigned short* wkb_b  = (unsigned short*)(W + 0);          // 4 MB  [16][256][512]
  unsigned short* wkT_b  = (unsigned short*)(W + 4194304);    // 2 MB  [16][512][128]
  unsigned short* wo_b16 = (unsigned short*)(W + 6291456);    // 8 MB
  unsigned short* qb     = (unsigned short*)(W + 14680064);   // 12 MB [NT][3072]
  unsigned short* wqa_b  = (unsigned short*)(W + 14680064);   // alias: dead before qb written
  unsigned short* ohead  = (unsigned short*)(W + 27262976);   // 8 MB  [NT][2048]
  unsigned short* kcatb  = (unsigned short*)(W + 35651584);   // 2.25 MB [NT][576]
  unsigned short* kcatT  = (unsigned short*)(W + 38010880);   // 2 MB  [B][512][1024]
  // loop scratch region (phase-5)
  unsigned short* qcat   = (unsigned short*)(W + 40108032);   // 4.5 MB [GG][NT][576]
  float*          scores = (float*)        (W + 44826624);    // 16 MB [GG*BB][SS][SS]
  unsigned short* o_mid  = (unsigned short*)(W + 61603840);   // 4 MB  [GG*BB][SS][512]
  // early-phase aliases inside the loop-scratch region
  unsigned short* xb     = (unsigned short*)(W + 40108032);   // 8 MB (dead before qcat/scores)
  float*          qn_f32 = (float*)        (W + 48496640);    // 12 MB (dead before scores)
  float*          kv_f32 = (float*)        (W + 48496640);    // 4.5 MB (after qn dead)
  unsigned short* qnb    = (unsigned short*)(W + 61079552);   // 6 MB (dead before o_mid)
  unsigned short* wqb_b  = (unsigned short*)(W + 67371008);   // 9 MB
  unsigned short* wkva_b = (unsigned short*)(W + 76808192);   // 2.25 MB  (end 79,167,488)

  const float inv_sqrt = 0.07216878364870323f;  // 1/sqrt(192)

  // conversions
  cvt_k<<<4096, 256, 0, stream>>>(x, xb, (long)NT * DIM / 4);
  cvt_k<<<3072, 256, 0, stream>>>(wq_a_w, wqa_b, (long)QR * DIM / 4);
  cvt_k<<<4608, 256, 0, stream>>>(wq_b_w, wqb_b, (long)3072 * QR / 4);
  cvt_k<<<1152, 256, 0, stream>>>(wkv_a_w, wkva_b, (long)576 * DIM / 4);
  cvt_k<<<2048, 256, 0, stream>>>(wk_b_w, wkb_b, (long)HH * 256 * KVR / 4);
  cvt_k<<<4096, 256, 0, stream>>>(wo_w, wo_b16, (long)DIM * DIM / 4);
  wkT_k<<<4096, 256, 0, stream>>>(wk_b_w, wkT_b);

  // q_a: qn = x @ wq_a^T  (fp32 out for rmsnorm)
  gemm_mfma<0,0><<<dim3(QR/128, NT/128, 1), 256, 0, stream>>>(
      xb, DIM, 0, wqa_b, DIM, 0, 0, qn_f32, QR, 0, NT, QR, DIM, wq_a_b, 1.f);
  rmsnorm_k<<<NT, 256, 0, stream>>>(qn_f32, QR, qnb, QR, q_norm_w, QR);
  // q_b: qb = qnb @ wq_b^T  (bf16 out)
  gemm_mfma<1,0><<<dim3(3072/128, NT/128, 1), 256, 0, stream>>>(
      qnb, QR, 0, wqb_b, QR, 0, 0, qb, 3072, 0, NT, 3072, QR, wq_b_b, 1.f);
  rope_q_k<<<4096, 256, 0, stream>>>(qb, cosT, sinT);
  // kv_a: kv = x @ wkv_a^T (fp32 out, N=576 edge)
  gemm_mfma<0,0><<<dim3(5, NT/128, 1), 256, 0, stream>>>(
      xb, DIM, 0, wkva_b, DIM, 0, 0, kv_f32, 576, 0, NT, 576, DIM, wkv_a_b, 1.f);
  rmsnorm_k<<<NT, 256, 0, stream>>>(kv_f32, 576, kcatb, 576, kv_norm_w, KVR);
  rope_k_k<<<256, 256, 0, stream>>>(kv_f32, kcatb, cosT, sinT);
  kcT_k<<<4096, 256, 0, stream>>>(kcatb, kcatT);

  for (int hg = 0; hg < HH / GG; ++hg) {
    int h0 = hg * GG;
    // q_abs: qcat[:, :512] = q_nope_h @ wkT[h]   (z = head in group)
    gemm_mfma<1,0><<<dim3(4, NT/128, GG), 256, 0, stream>>>(
        qb + h0 * QKD, 3072, QKD,
        wkT_b + (long)h0 * KVR * DN, DN, (long)KVR * DN, 0,
        qcat, 576, (long)NT * 576, NT, KVR, DN, nullptr, 1.f);
    copy_pe_k<<<1024, 256, 0, stream>>>(qb, qcat, h0);
    // scores = qcat @ kcat^T / sqrt(192) + causal   (z = h*BB + b)
    gemm_mfma<0,1><<<dim3(8, 8, GG*BB), 256, 0, stream>>>(
        qcat, 576, (long)SS * 576,
        kcatb, 576, (long)SS * 576, BB,
        scores, SS, (long)SS * SS, SS, SS, 576, nullptr, inv_sqrt);
    softmax_k<<<GG*BB*SS, 256, 0, stream>>>(scores);
    // o_mid = P @ kvn   (A = bf16 P with lda 2048, B = kcatT)
    gemm_mfma<1,0><<<dim3(4, 8, GG*BB), 256, 0, stream>>>(
        (const unsigned short*)scores, 2048, (long)SS * SS * 2,
        kcatT, SS, (long)KVR * SS, BB,
        o_mid, KVR, (long)SS * KVR, SS, KVR, SS, nullptr, 1.f);
    // o_head[:, h*128..] = o_mid @ wkv_b_v^T
    gemm_mfma<1,0><<<dim3(1, NT/128, GG), 256, 0, stream>>>(
        o_mid, KVR, (long)NT * KVR,
        wkb_b + ((long)h0 * 256 + DN) * KVR, KVR, (long)256 * KVR, 0,
        ohead + h0 * DV, HH * DV, DV, NT, DV, KVR, nullptr, 1.f);
  }

  // out = o_head @ wo^T + b   (fp32 out)
  gemm_mfma<0,0><<<dim3(DIM/128, NT/128, 1), 256, 0, stream>>>(
      ohead, 2048, 0, wo_b16, 2048, 0, 0, out, DIM, 0, NT, DIM, 2048, wo_bias, 1.f);
}

// Round 3
// 618.418 us; speedup vs baseline: 10.7839x; 1.4758x over previous
//
#include <hip/hip_runtime.h>
#include <hip/hip_bf16.h>
#include <math.h>

#define BB 2
#define SS 1024
#define DIM 2048
#define HH 16
#define QR 1536
#define KVR 512
#define DN 128
#define DR 64
#define DV 128
#define QKD 192
#define NT (BB*SS)
#define GG 4   // heads per group

typedef __attribute__((ext_vector_type(8))) short bhalf8;
typedef __attribute__((ext_vector_type(4))) float f32x4;

__device__ __forceinline__ unsigned short f2b(float f) {
  union { float f; unsigned u; } v; v.f = f;
  unsigned r = v.u + 0x7fffu + ((v.u >> 16) & 1u);
  return (unsigned short)(r >> 16);
}
__device__ __forceinline__ float b2f(unsigned short h) {
  union { unsigned u; float f; } v; v.u = ((unsigned)h) << 16;
  return v.f;
}

__device__ __forceinline__ void gload16(const void* g, void* l) {
  __builtin_amdgcn_global_load_lds((const __attribute__((address_space(1))) void*)g,
                                   (__attribute__((address_space(3))) void*)l, 16, 0, 0);
}

// ---------------- f32 -> bf16 convert ----------------
__global__ void cvt_k(const float* __restrict__ in, unsigned short* __restrict__ out, long n4) {
  long i = (long)blockIdx.x * 256 + threadIdx.x;
  if (i >= n4) return;
  float4 v = ((const float4*)in)[i];
  ushort4 o; o.x = f2b(v.x); o.y = f2b(v.y); o.z = f2b(v.z); o.w = f2b(v.w);
  ((ushort4*)out)[i] = o;
}

// wkT[h][c][d] = bf16(wk[h][d][c]), d<128, c<512
__global__ void wkT_k(const float* __restrict__ wk, unsigned short* __restrict__ wkT) {
  int idx = blockIdx.x * 256 + threadIdx.x;
  int d = idx & 127, c = (idx >> 7) & 511, h = idx >> 16;
  wkT[idx] = f2b(wk[((long)h * 256 + d) * 512 + c]);
}

// kcatT[b][c][t] = kcatb[b][t][c], c<512
__global__ void kcT_k(const unsigned short* __restrict__ kc, unsigned short* __restrict__ kt) {
  int idx = blockIdx.x * 256 + threadIdx.x;
  int t = idx & 1023, c = (idx >> 10) & 511, b = idx >> 19;
  kt[idx] = kc[((long)b * SS + t) * 576 + c];
}

// ---------------- MFMA GEMM: C = scale*A@B^T + bias (+causal) ----------------
// A: M x K bf16 (lda), B: N x K bf16 (ldb). 128x128 tile, BK=32, 4 waves.
// XMODE: 0 = blockIdx as-is; 1 = XCD decode for 8x8x8 grid; 2 = for 4x8x8 grid.
// KC: 1 = causal K limit (K_eff = m0+128).
template<int OBF, int CAUSAL, int XMODE, int KC>
__global__ __launch_bounds__(256) void gemm_mfma(
    const unsigned short* __restrict__ A, int lda, long sA,
    const unsigned short* __restrict__ B, int ldb, long sB, int bmod,
    void* __restrict__ C, int ldc, long sC,
    int M, int N, int K, const float* __restrict__ bias, float scale)
{
  int bx, by, bz;
  if (XMODE == 0) { bx = blockIdx.x; by = blockIdx.y; bz = blockIdx.z; }
  else {
    int L = blockIdx.x, xcd = L & 7, slot = L >> 3;
    if (XMODE == 1) {            // 8 x 8 x 8
      bx = ((xcd & 1) << 2) | (slot & 3);
      by = (((xcd >> 1) & 1) << 2) | ((slot >> 2) & 3);
      bz = (((xcd >> 2) & 1) << 2) | ((slot >> 4) & 3);
    } else {                     // 4 x 8 x 8
      bx = ((xcd & 1) << 1) | (slot & 1);
      by = (((xcd >> 1) & 1) << 2) | ((slot >> 1) & 3);
      bz = (((xcd >> 2) & 1) << 2) | ((slot >> 3) & 3);
    }
  }
  const int m0 = by * 128, n0 = bx * 128;
  if (CAUSAL && n0 > m0 + 127) return;   // upper-triangle block: nothing to do

  A += (long)bz * sA;
  B += (long)(bmod ? (bz % bmod) : bz) * sB;

  __shared__ unsigned short As[4096];
  __shared__ unsigned short Bs[4096];
  const int tid = threadIdx.x, l = tid & 63, w = tid >> 6;
  const int wr = w >> 1, wc = w & 1;
  const int rA = l >> 2;                               // row within 16-row chunk
  const int c8 = (((l & 3) ^ ((l >> 2) & 3)) << 3);    // swizzled k-slot (source side)

  f32x4 acc[4][4] = {};

  const unsigned short* Ab0 = A + (long)(m0 + w * 16 + rA) * lda + c8;
  const unsigned short* Ab1 = Ab0 + (long)64 * lda;
  int nb0 = n0 + w * 16 + rA;      if (nb0 > N - 1) nb0 = N - 1;
  int nb1 = n0 + 64 + w * 16 + rA; if (nb1 > N - 1) nb1 = N - 1;
  const unsigned short* Bb0 = B + (long)nb0 * ldb + c8;
  const unsigned short* Bb1 = B + (long)nb1 * ldb + c8;

  const int ko = (((l >> 4) ^ (l & 3)) << 3);          // swizzled k-slot (read side)
  const int Kend = KC ? ((m0 + 128 < K) ? m0 + 128 : K) : K;

  for (int k0 = 0; k0 < Kend; k0 += 32) {
    gload16(Ab0 + k0, &As[w * 512]);
    gload16(Ab1 + k0, &As[(w + 4) * 512]);
    gload16(Bb0 + k0, &Bs[w * 512]);
    gload16(Bb1 + k0, &Bs[(w + 4) * 512]);
    __syncthreads();
    bhalf8 af[4], bv[4];
#pragma unroll
    for (int m = 0; m < 4; ++m) {
      af[m] = *(const bhalf8*)&As[(wr * 64 + m * 16 + (l & 15)) * 32 + ko];
      bv[m] = *(const bhalf8*)&Bs[(wc * 64 + m * 16 + (l & 15)) * 32 + ko];
    }
#pragma unroll
    for (int m = 0; m < 4; ++m)
#pragma unroll
      for (int n = 0; n < 4; ++n)
        acc[m][n] = __builtin_amdgcn_mfma_f32_16x16x32_bf16(af[m], bv[n], acc[m][n], 0, 0, 0);
    __syncthreads();
  }

  const int ro = (l >> 4) << 2;
  const int co = l & 15;
#pragma unroll
  for (int m = 0; m < 4; ++m) {
    int row = m0 + wr * 64 + m * 16 + ro;
#pragma unroll
    for (int n = 0; n < 4; ++n) {
      int col = n0 + wc * 64 + n * 16 + co;
      if (col < N) {
        float bvl = bias ? bias[col] : 0.f;
#pragma unroll
        for (int r = 0; r < 4; ++r) {
          float v = acc[m][n][r] * scale + bvl;
          if (CAUSAL && (row + r) < col) v += -1e9f;
          long off = (long)bz * sC + (long)(row + r) * ldc + col;
          if (OBF) ((unsigned short*)C)[off] = f2b(v);
          else     ((float*)C)[off] = v;
        }
      }
    }
  }
}

// ---------------- RMSNorm fp32 -> bf16 ----------------
__global__ void rmsnorm_k(const float* __restrict__ in, int ldin,
                          unsigned short* __restrict__ out, int ldout,
                          const float* __restrict__ w, int N) {
  long row = blockIdx.x;
  const float* x = in + row * ldin;
  unsigned short* y = out + row * ldout;
  float ss = 0.f;
  for (int i = threadIdx.x; i < N; i += 256) { float u = x[i]; ss += u * u; }
  for (int o = 32; o > 0; o >>= 1) ss += __shfl_down(ss, o);
  __shared__ float red[4];
  int lane = threadIdx.x & 63, wid = threadIdx.x >> 6;
  if (lane == 0) red[wid] = ss;
  __syncthreads();
  float r = rsqrtf((red[0] + red[1] + red[2] + red[3]) / (float)N + 1e-6f);
  for (int i = threadIdx.x; i < N; i += 256) y[i] = f2b(x[i] * r * w[i]);
}

// ---------------- RoPE on q_pe, in-place bf16 ----------------
__global__ void rope_q_k(unsigned short* __restrict__ qb,
                         const float* __restrict__ cosT, const float* __restrict__ sinT) {
  int idx = blockIdx.x * 256 + threadIdx.x;
  int d = idx & 31, h = (idx >> 5) & 15, t = idx >> 9, s = t & (SS - 1);
  unsigned short* p = qb + (long)t * 3072 + h * QKD + DN;
  float x1 = b2f(p[d]), x2 = b2f(p[d + 32]);
  float c1 = cosT[s * DR + d],      s1 = sinT[s * DR + d];
  float c2 = cosT[s * DR + 32 + d], s2 = sinT[s * DR + 32 + d];
  p[d]      = f2b(x1 * c1 - x2 * s1);
  p[d + 32] = f2b(x2 * c2 + x1 * s2);
}

// ---------------- RoPE on k_pe ----------------
__global__ void rope_k_k(const float* __restrict__ kv, unsigned short* __restrict__ kc,
                         const float* __restrict__ cosT, const float* __restrict__ sinT) {
  int idx = blockIdx.x * 256 + threadIdx.x;
  int d = idx & 31, t = idx >> 5, s = t & (SS - 1);
  const float* p = kv + (long)t * 576 + 512;
  float x1 = p[d], x2 = p[d + 32];
  float c1 = cosT[s * DR + d],      s1 = sinT[s * DR + d];
  float c2 = cosT[s * DR + 32 + d], s2 = sinT[s * DR + 32 + d];
  unsigned short* o = kc + (long)t * 576 + 512;
  o[d]      = f2b(x1 * c1 - x2 * s1);
  o[d + 32] = f2b(x2 * c2 + x1 * s2);
}

// ---------------- copy q_pe (heads h0..h0+GG) into qcat cols 512..575 ----------------
__global__ void copy_pe_k(const unsigned short* __restrict__ qb,
                          unsigned short* __restrict__ qcat, int h0) {
  int idx = blockIdx.x * 256 + threadIdx.x;   // GG*NT*64
  int d = idx & 63, t = (idx >> 6) & (NT - 1), z = idx >> 17;
  qcat[((long)z * NT + t) * 576 + 512 + d] = qb[(long)t * 3072 + (h0 + z) * QKD + DN + d];
}

// ---------------- causal softmax fp32 row -> bf16 in place ----------------
__global__ void softmax_k(float* __restrict__ sc) {
  long row = blockIdx.x;          // z*1024 + r
  int r = (int)(row & (SS - 1));
  float* p = sc + row * SS;
  const int t = threadIdx.x;
  float v[4];
#pragma unroll
  for (int j = 0; j < 4; ++j) {
    int col = t + j * 256;
    v[j] = (col <= r) ? p[col] : -1e30f;
  }
  float mx = fmaxf(fmaxf(v[0], v[1]), fmaxf(v[2], v[3]));
  for (int o = 32; o > 0; o >>= 1) mx = fmaxf(mx, __shfl_down(mx, o));
  __shared__ float red[4];
  __shared__ float red2[4];
  int lane = t & 63, wid = t >> 6;
  if (lane == 0) red[wid] = mx;
  __syncthreads();
  mx = fmaxf(fmaxf(red[0], red[1]), fmaxf(red[2], red[3]));
  float sum = 0.f;
#pragma unroll
  for (int j = 0; j < 4; ++j) { v[j] = __expf(v[j] - mx); sum += v[j]; }
  for (int o = 32; o > 0; o >>= 1) sum += __shfl_down(sum, o);
  if (lane == 0) red2[wid] = sum;
  __syncthreads();
  float inv = 1.f / (red2[0] + red2[1] + red2[2] + red2[3]);
  unsigned short* o16 = (unsigned short*)p;
#pragma unroll
  for (int j = 0; j < 4; ++j) o16[t + j * 256] = f2b(v[j] * inv);
}

// ---------------- launch ----------------
extern "C" void kernel_launch(void* const* d_in, const int* in_sizes, int n_in,
                              void* d_out, int out_size, void* d_ws, size_t ws_size,
                              hipStream_t stream) {
  const float* x        = (const float*)d_in[0];
  const float* wq_a_w   = (const float*)d_in[2];
  const float* wq_a_b   = (const float*)d_in[3];
  const float* q_norm_w = (const float*)d_in[4];
  const float* wq_b_w   = (const float*)d_in[5];
  const float* wq_b_b   = (const float*)d_in[6];
  const float* wkv_a_w  = (const float*)d_in[7];
  const float* wkv_a_b  = (const float*)d_in[8];
  const float* kv_norm_w= (const float*)d_in[9];
  const float* wk_b_w   = (const float*)d_in[10];
  const float* wo_w     = (const float*)d_in[11];
  const float* wo_bias  = (const float*)d_in[12];
  const float* cosT     = (const float*)d_in[13];
  const float* sinT     = (const float*)d_in[14];
  float* out = (float*)d_out;

  char* W = (char*)d_ws;
  // persistent
  unsigned short* wkb_b  = (unsigned short*)(W + 0);          // 4 MB  [16][256][512]
  unsigned short* wkT_b  = (unsigned short*)(W + 4194304);    // 2 MB  [16][512][128]
  unsigned short* qb     = (unsigned short*)(W + 6291456);    // 12 MB [NT][3072]
  unsigned short* wqa_b  = (unsigned short*)(W + 6291456);    // alias: dead before qb written
  unsigned short* ohead  = (unsigned short*)(W + 18874368);   // 8 MB  [NT][2048]
  unsigned short* kcatb  = (unsigned short*)(W + 27262976);   // 2.25 MB [NT][576]
  unsigned short* kcatT  = (unsigned short*)(W + 29622272);   // 2 MB  [B][512][1024]
  // loop region
  unsigned short* qcat   = (unsigned short*)(W + 31719424);   // 9 MB [GG][NT][576]
  unsigned short* o_mid  = (unsigned short*)(W + 31719424);   // 8 MB alias (qcat dead)
  unsigned short* wo_b16 = (unsigned short*)(W + 31719424);   // 8 MB alias (after loop)
  float*          scores = (float*)        (W + 41156608);    // 32 MB [GG*BB][SS][SS]
  // pre-loop aliases inside loop region
  unsigned short* xb     = (unsigned short*)(W + 31719424);   // 8 MB (dead before qcat)
  float*          qn_f32 = (float*)        (W + 41156608);    // 12 MB
  float*          kv_f32 = (float*)        (W + 41156608);    // 4.5 MB (after qn dead)
  unsigned short* qnb    = (unsigned short*)(W + 53739520);   // 6 MB
  unsigned short* wqb_b  = (unsigned short*)(W + 60030976);   // 9 MB
  unsigned short* wkva_b = (unsigned short*)(W + 69468160);   // 2.25 MB (end 71,827,456)

  const float inv_sqrt = 0.07216878364870323f;  // 1/sqrt(192)

  // conversions (wo converted after the loop, into the dead o_mid region)
  cvt_k<<<4096, 256, 0, stream>>>(x, xb, (long)NT * DIM / 4);
  cvt_k<<<3072, 256, 0, stream>>>(wq_a_w, wqa_b, (long)QR * DIM / 4);
  cvt_k<<<4608, 256, 0, stream>>>(wq_b_w, wqb_b, (long)3072 * QR / 4);
  cvt_k<<<1152, 256, 0, stream>>>(wkv_a_w, wkva_b, (long)576 * DIM / 4);
  cvt_k<<<2048, 256, 0, stream>>>(wk_b_w, wkb_b, (long)HH * 256 * KVR / 4);
  wkT_k<<<4096, 256, 0, stream>>>(wk_b_w, wkT_b);

  // q_a: qn = x @ wq_a^T (fp32 out)
  gemm_mfma<0,0,0,0><<<dim3(QR/128, NT/128, 1), 256, 0, stream>>>(
      xb, DIM, 0, wqa_b, DIM, 0, 0, qn_f32, QR, 0, NT, QR, DIM, wq_a_b, 1.f);
  rmsnorm_k<<<NT, 256, 0, stream>>>(qn_f32, QR, qnb, QR, q_norm_w, QR);
  // q_b: qb = qnb @ wq_b^T (bf16 out)
  gemm_mfma<1,0,0,0><<<dim3(3072/128, NT/128, 1), 256, 0, stream>>>(
      qnb, QR, 0, wqb_b, QR, 0, 0, qb, 3072, 0, NT, 3072, QR, wq_b_b, 1.f);
  rope_q_k<<<4096, 256, 0, stream>>>(qb, cosT, sinT);
  // kv_a: kv = x @ wkv_a^T (fp32 out)
  gemm_mfma<0,0,0,0><<<dim3(5, NT/128, 1), 256, 0, stream>>>(
      xb, DIM, 0, wkva_b, DIM, 0, 0, kv_f32, 576, 0, NT, 576, DIM, wkv_a_b, 1.f);
  rmsnorm_k<<<NT, 256, 0, stream>>>(kv_f32, 576, kcatb, 576, kv_norm_w, KVR);
  rope_k_k<<<256, 256, 0, stream>>>(kv_f32, kcatb, cosT, sinT);
  kcT_k<<<4096, 256, 0, stream>>>(kcatb, kcatT);

  for (int hg = 0; hg < HH / GG; ++hg) {
    int h0 = hg * GG;
    // q_abs: qcat[:, :512] = q_nope_h @ wkT[h]
    gemm_mfma<1,0,0,0><<<dim3(4, NT/128, GG), 256, 0, stream>>>(
        qb + h0 * QKD, 3072, QKD,
        wkT_b + (long)h0 * KVR * DN, DN, (long)KVR * DN, 0,
        qcat, 576, (long)NT * 576, NT, KVR, DN, nullptr, 1.f);
    copy_pe_k<<<2048, 256, 0, stream>>>(qb, qcat, h0);
    // scores = qcat @ kcat^T / sqrt(192) + causal   (z = g*BB + b, XCD decode, tri-skip)
    gemm_mfma<0,1,1,0><<<dim3(512, 1, 1), 256, 0, stream>>>(
        qcat, 576, (long)SS * 576,
        kcatb, 576, (long)SS * 576, BB,
        scores, SS, (long)SS * SS, SS, SS, 576, nullptr, inv_sqrt);
    softmax_k<<<GG*BB*SS, 256, 0, stream>>>(scores);
    // o_mid = P @ kvn  (bf16 P rows inside fp32 score rows; causal-K)
    gemm_mfma<1,0,2,1><<<dim3(256, 1, 1), 256, 0, stream>>>(
        (const unsigned short*)scores, 2048, (long)SS * SS * 2,
        kcatT, SS, (long)KVR * SS, BB,
        o_mid, KVR, (long)SS * KVR, SS, KVR, SS, nullptr, 1.f);
    // o_head[:, (h0+z)*128..] = o_mid @ wkv_b_v^T
    gemm_mfma<1,0,0,0><<<dim3(1, NT/128, GG), 256, 0, stream>>>(
        o_mid, KVR, (long)NT * KVR,
        wkb_b + ((long)h0 * 256 + DN) * KVR, KVR, (long)256 * KVR, 0,
        ohead + h0 * DV, HH * DV, DV, NT, DV, KVR, nullptr, 1.f);
  }

  // convert wo now (o_mid/qcat dead), then out = o_head @ wo^T + b (fp32 out)
  cvt_k<<<4096, 256, 0, stream>>>(wo_w, wo_b16, (long)DIM * DIM / 4);
  gemm_mfma<0,0,0,0><<<dim3(DIM/128, NT/128, 1), 256, 0, stream>>>(
      ohead, 2048, 0, wo_b16, 2048, 0, 0, out, DIM, 0, NT, DIM, 2048, wo_bias, 1.f);
}